// Round 5
// baseline (292.353 us; speedup 1.0000x reference)
//
#include <hip/hip_runtime.h>

#define C_DIM 10000
#define C4 2500                  // float4s per row
#define HALF4 1250               // float4s per half-row
#define ITQ1 5                   // prefetch iters per wave in sweep (covers 313)
#define NIT4 40                  // full-row iters for one wave (fallbacks)
#define TAU 1.0f
#define PIV_HI 2.0f
#define PIV_LO 1.0f
#define CAPW 64                  // K1 per-wave candidate cap (mean 28.4, 6.8 sigma)
#define CAPH 256                 // per-half scratch slot (4*CAPW)
#define ROWCAP 512               // per-row scratch slot (2*CAPH)
#define SENT 0xFFFFFFFFu

// Monotone bijection float -> uint32 (larger float => larger key)
__device__ __forceinline__ unsigned flip_key(float f) {
    unsigned u = __float_as_uint(f);
    return (u & 0x80000000u) ? ~u : (u | 0x80000000u);
}
__device__ __forceinline__ float unflip_key(unsigned k) {
    unsigned u = (k & 0x80000000u) ? (k & 0x7fffffffu) : ~k;
    return __uint_as_float(u);
}
// # of set bits in m strictly below my lane (64-lane)
__device__ __forceinline__ int mbcnt64(unsigned long long m) {
    return (int)__builtin_amdgcn_mbcnt_hi((unsigned)(m >> 32),
               __builtin_amdgcn_mbcnt_lo((unsigned)(m & 0xffffffffu), 0u));
}

__global__ void zero_out_kernel(float* out, int n) {
    int i = blockIdx.x * blockDim.x + threadIdx.x;
    if (i < n) out[i] = 0.f;
}

// Wave-uniform radix bin pick: each lane owns 4 bins (hv), suffix-scan across
// the wave, exactly one lane picks; result broadcast via shuffles. No barrier.
__device__ __forceinline__ void wave_pick(uint4 hv, int lane, int shift,
                                          unsigned& prefix, unsigned& kr, unsigned& cnt) {
    unsigned loc = hv.x + hv.y + hv.z + hv.w;
    unsigned suf = loc;
    #pragma unroll
    for (int off = 1; off < 64; off <<= 1) {
        unsigned o = (unsigned)__shfl_down((int)suf, off);
        if (lane + off < 64) suf += o;
    }
    unsigned sufex = suf - loc;              // candidates in bins strictly above my 4
    unsigned s3 = sufex + hv.w;
    unsigned s2 = s3 + hv.z;
    unsigned s1 = s2 + hv.y;
    unsigned s0 = s1 + hv.x;
    int bsel = -1; unsigned nkr = 0u, ncnt = 0u;
    if      (s3 >= kr && s3 - hv.w < kr) { bsel = 4 * lane + 3; nkr = kr - (s3 - hv.w); ncnt = hv.w; }
    else if (s2 >= kr && s2 - hv.z < kr) { bsel = 4 * lane + 2; nkr = kr - (s2 - hv.z); ncnt = hv.z; }
    else if (s1 >= kr && s1 - hv.y < kr) { bsel = 4 * lane + 1; nkr = kr - (s1 - hv.y); ncnt = hv.y; }
    else if (s0 >= kr && s0 - hv.x < kr) { bsel = 4 * lane + 0; nkr = kr - (s0 - hv.x); ncnt = hv.x; }
    unsigned long long pm = __ballot(bsel >= 0);
    int src = __ffsll((unsigned long long)pm) - 1;   // exactly one lane picked
    prefix |= ((unsigned)__shfl(bsel, src)) << shift;
    kr  = (unsigned)__shfl((int)nkr, src);
    cnt = (unsigned)__shfl((int)ncnt, src);
}

// ================= K1: streaming sweep, one block per HALF-row =================
// 8192 blocks x 256 thr; 4 waves each own ~1/8 of the row (312/313 float4s).
// Register-prefetch all 10 loads, compute z/madj partials, ballot-compact
// cands >= PIV_HI into per-wave LDS then copy to deterministic scratch segments.
__global__ __launch_bounds__(256, 6) void sweep_kernel(
    const float* __restrict__ logit, const float* __restrict__ lcn,
    unsigned* __restrict__ g_keys, unsigned short* __restrict__ g_idx,
    unsigned* __restrict__ g_cnt, float* __restrict__ g_z, float* __restrict__ g_m) {
    __shared__ unsigned ck[4][CAPW];
    __shared__ unsigned short ci[4][CAPW];
    __shared__ unsigned sh_nb[4];
    __shared__ float sh_z[4], sh_m[4];

    const int tid = threadIdx.x;
    const int lane = tid & 63;
    const int wid = tid >> 6;
    const int row = blockIdx.x >> 1;
    const int half = blockIdx.x & 1;
    const float* lrow = logit + (size_t)row * C_DIM;

    // wave segment within the half: w0,w1 -> 313; w2,w3 -> 312 float4s
    const int base4 = half * HALF4 + wid * 312 + (wid < 2 ? wid : 2);
    const int segn = 312 + (wid < 2 ? 1 : 0);

    // ---- register prefetch: all 10 loads in flight
    float4 fv[ITQ1], lv[ITQ1];
    #pragma unroll
    for (int it = 0; it < ITQ1; ++it) {
        const int j4l = it * 64 + lane;
        if (j4l < segn) {
            fv[it] = ((const float4*)lrow)[base4 + j4l];
            lv[it] = ((const float4*)lcn)[base4 + j4l];
        } else {
            fv[it] = make_float4(-1e30f, -1e30f, -1e30f, -1e30f);
            lv[it] = make_float4(0.f, 0.f, 0.f, 0.f);
        }
    }

    float z0 = 0.f, z1 = 0.f, z2 = 0.f, z3 = 0.f;
    float mA = -__builtin_inff(), mB = -__builtin_inff();
    unsigned nb = 0u;
    #pragma unroll
    for (int it = 0; it < ITQ1; ++it) {
        const float4 f = fv[it], l = lv[it];
        const float a0 = f.x + TAU * l.x, a1 = f.y + TAU * l.y;
        const float a2 = f.z + TAU * l.z, a3 = f.w + TAU * l.w;
        z0 += __expf(a0); z1 += __expf(a1);      // exp(-1e30)=0 for pad lanes
        z2 += __expf(a2); z3 += __expf(a3);
        mA = fmaxf(mA, fmaxf(a0, a1));
        mB = fmaxf(mB, fmaxf(a2, a3));
        const int j = 4 * (base4 + it * 64 + lane);
        unsigned long long m;
        m = __ballot(f.x >= PIV_HI);
        if (f.x >= PIV_HI) { unsigned p = nb + (unsigned)mbcnt64(m); if (p < CAPW) { ck[wid][p] = __float_as_uint(f.x); ci[wid][p] = (unsigned short)(j + 0); } }
        nb += (unsigned)__popcll(m);
        m = __ballot(f.y >= PIV_HI);
        if (f.y >= PIV_HI) { unsigned p = nb + (unsigned)mbcnt64(m); if (p < CAPW) { ck[wid][p] = __float_as_uint(f.y); ci[wid][p] = (unsigned short)(j + 1); } }
        nb += (unsigned)__popcll(m);
        m = __ballot(f.z >= PIV_HI);
        if (f.z >= PIV_HI) { unsigned p = nb + (unsigned)mbcnt64(m); if (p < CAPW) { ck[wid][p] = __float_as_uint(f.z); ci[wid][p] = (unsigned short)(j + 2); } }
        nb += (unsigned)__popcll(m);
        m = __ballot(f.w >= PIV_HI);
        if (f.w >= PIV_HI) { unsigned p = nb + (unsigned)mbcnt64(m); if (p < CAPW) { ck[wid][p] = __float_as_uint(f.w); ci[wid][p] = (unsigned short)(j + 3); } }
        nb += (unsigned)__popcll(m);
    }
    float z = (z0 + z1) + (z2 + z3);
    float madj = fmaxf(mA, mB);
    #pragma unroll
    for (int off = 32; off; off >>= 1) {
        z += __shfl_down(z, off);
        madj = fmaxf(madj, __shfl_down(madj, off));
    }
    if (lane == 0) { sh_nb[wid] = nb; sh_z[wid] = z; sh_m[wid] = madj; }
    __syncthreads();

    const unsigned n0 = sh_nb[0], n1 = sh_nb[1], n2 = sh_nb[2], n3 = sh_nb[3];
    const bool ovf = (n0 > CAPW) | (n1 > CAPW) | (n2 > CAPW) | (n3 > CAPW);
    if (!ovf) {
        // deterministic compact copy: wave segments concatenated in wid order
        const unsigned pre = (wid > 0 ? n0 : 0u) + (wid > 1 ? n1 : 0u) + (wid > 2 ? n2 : 0u);
        const unsigned nbw = sh_nb[wid];
        const size_t dst = (size_t)row * ROWCAP + (size_t)half * CAPH + pre;
        for (unsigned i = lane; i < nbw; i += 64) {
            g_keys[dst + i] = ck[wid][i];
            g_idx[dst + i] = ci[wid][i];
        }
    }
    if (tid == 0) {
        g_cnt[2 * row + half] = ovf ? SENT : (n0 + n1 + n2 + n3);
        g_z[2 * row + half] = sh_z[0] + sh_z[1] + sh_z[2] + sh_z[3];
        g_m[2 * row + half] = fmaxf(fmaxf(sh_z ? sh_m[0] : sh_m[0], sh_m[1]), fmaxf(sh_m[2], sh_m[3]));
    }
}

// ================= K2: select + masked sum + loss, one WAVE per row =================
__global__ __launch_bounds__(64, 8) void select_kernel(
    const float* __restrict__ logit, const int* __restrict__ target,
    const float* __restrict__ lcn, const int* __restrict__ kpc,
    const unsigned* __restrict__ g_keys, const unsigned short* __restrict__ g_idx,
    const unsigned* __restrict__ g_cnt, const float* __restrict__ g_z,
    const float* __restrict__ g_m, float* __restrict__ out, int B) {
    __shared__ unsigned k2k[ROWCAP];
    __shared__ unsigned short k2i[ROWCAP];
    __shared__ unsigned hist[256];

    const int lane = threadIdx.x;                // 64-thread block = one wave
    const int row = blockIdx.x;
    const float* lrow = logit + (size_t)row * C_DIM;

    const int t = target[row];
    int k = kpc[t]; if (k > C_DIM) k = C_DIM;
    const float logit_t = lrow[t];
    const float lcn_t = lcn[t];
    const unsigned c0 = g_cnt[2 * row], c1 = g_cnt[2 * row + 1];
    float Z = g_z[2 * row] + g_z[2 * row + 1];
    const float madj = fmaxf(g_m[2 * row], g_m[2 * row + 1]);

    const bool path0 = (c0 != SENT) && (c1 != SENT) && (c0 + c1 >= (unsigned)k);
    unsigned n = 0u;
    float thresh;

    if (path0) {
        // stage candidates to LDS (halves concatenated, deterministic order)
        n = c0 + c1;
        const size_t b0 = (size_t)row * ROWCAP;
        for (unsigned i = lane; i < c0; i += 64) { k2k[i] = g_keys[b0 + i]; k2i[i] = g_idx[b0 + i]; }
        for (unsigned i = lane; i < c1; i += 64) { k2k[c0 + i] = g_keys[b0 + CAPH + i]; k2i[c0 + i] = g_idx[b0 + CAPH + i]; }
        // exact byte-radix select (keys all >= 2.0 > 0 -> uint order); wave-sync
        unsigned prefix = 0u, kr = (unsigned)k, cnt = n, kmask = 0u;
        for (int q = 0; q < 4; ++q) {
            if (cnt == 1u) break;
            const int shift = 24 - 8 * q;
            *(uint4*)&hist[4 * lane] = make_uint4(0u, 0u, 0u, 0u);
            for (unsigned i = lane; i < n; i += 64) {
                unsigned kk = k2k[i];
                if ((kk & kmask) == prefix) atomicAdd(&hist[(kk >> shift) & 0xFFu], 1u);
            }
            uint4 hv = *(const uint4*)&hist[4 * lane];
            wave_pick(hv, lane, shift, prefix, kr, cnt);
            kmask |= (0xFFu << shift);
        }
        if (cnt == 1u && kmask != 0xFFFFFFFFu) {     // unique survivor: full bits
            unsigned found = 0u;
            for (unsigned i = lane; i < n; i += 64) {
                unsigned kk = k2k[i];
                if ((kk & kmask) == prefix) found = kk;
            }
            #pragma unroll
            for (int off = 32; off; off >>= 1) found |= (unsigned)__shfl_xor((int)found, off);
            prefix = found;
        }
        thresh = __uint_as_float(prefix);
    } else {
        // exact full-row radix on flipped keys (never hot)
        unsigned prefix = 0u, kr = (unsigned)k, cnt = 0u;
        for (int p = 0; p < 4; ++p) {
            const int shift = 24 - 8 * p;
            const unsigned pmask = p ? (0xFFFFFFFFu << (shift + 8)) : 0u;
            *(uint4*)&hist[4 * lane] = make_uint4(0u, 0u, 0u, 0u);
            for (int it = 0; it < NIT4; ++it) {
                const int j4 = it * 64 + lane;
                if (j4 < C4) {
                    float4 f = ((const float4*)lrow)[j4];
                    unsigned kk;
                    kk = flip_key(f.x); if ((kk & pmask) == prefix) atomicAdd(&hist[(kk >> shift) & 0xFFu], 1u);
                    kk = flip_key(f.y); if ((kk & pmask) == prefix) atomicAdd(&hist[(kk >> shift) & 0xFFu], 1u);
                    kk = flip_key(f.z); if ((kk & pmask) == prefix) atomicAdd(&hist[(kk >> shift) & 0xFFu], 1u);
                    kk = flip_key(f.w); if ((kk & pmask) == prefix) atomicAdd(&hist[(kk >> shift) & 0xFFu], 1u);
                }
            }
            uint4 hv = *(const uint4*)&hist[4 * lane];
            wave_pick(hv, lane, shift, prefix, kr, cnt);
        }
        thresh = unflip_key(prefix);
    }

    const bool rare = fabsf(madj) > 80.f;        // exp over/underflow guard
    float sm = 0.f, zloc = 0.f;
    if (!rare) {
        if (path0) {
            for (unsigned i = lane; i < n; i += 64) {
                const float v = __uint_as_float(k2k[i]);
                if (v >= thresh) sm += __expf(v + TAU * lcn[k2i[i]]);
            }
        } else {
            for (int it = 0; it < NIT4; ++it) {
                const int j4 = it * 64 + lane;
                if (j4 < C4) {
                    float4 f = ((const float4*)lrow)[j4];
                    float4 l = ((const float4*)lcn)[j4];
                    if (f.x >= thresh) sm += __expf(f.x + TAU * l.x);
                    if (f.y >= thresh) sm += __expf(f.y + TAU * l.y);
                    if (f.z >= thresh) sm += __expf(f.z + TAU * l.z);
                    if (f.w >= thresh) sm += __expf(f.w + TAU * l.w);
                }
            }
        }
    } else {
        // exact re-sweep with max subtraction (never hot)
        for (int it = 0; it < NIT4; ++it) {
            const int j4 = it * 64 + lane;
            if (j4 < C4) {
                float4 f = ((const float4*)lrow)[j4];
                float4 l = ((const float4*)lcn)[j4];
                float e;
                e = __expf(f.x + TAU * l.x - madj); zloc += e; if (f.x >= thresh) sm += e;
                e = __expf(f.y + TAU * l.y - madj); zloc += e; if (f.y >= thresh) sm += e;
                e = __expf(f.z + TAU * l.z - madj); zloc += e; if (f.z >= thresh) sm += e;
                e = __expf(f.w + TAU * l.w - madj); zloc += e; if (f.w >= thresh) sm += e;
            }
        }
    }

    #pragma unroll
    for (int off = 32; off; off >>= 1) {
        sm += __shfl_down(sm, off);
        zloc += __shfl_down(zloc, off);
    }
    if (lane == 0) {
        if (rare) Z = zloc;
        const float adj_t = logit_t + TAU * lcn_t;
        const float sub = rare ? madj : 0.f;
        const float lpt = adj_t - sub - __logf(Z);             // log_p_adj[target]
        const float p_num = ((logit_t >= thresh) ? __expf(lpt) : 0.f) + 1e-6f;
        const float Smask = sm / Z + (float)C_DIM * 1e-6f;
        const float loss = 0.5f * (-lpt + __logf(Smask) - __logf(p_num));
        atomicAdd(out, loss / (float)B);
    }
}

// ================= Fallback: round-4 monolithic kernel (ws too small) =================
#define MONO_CAP 512
#define MONO_SEGQ 625
#define MONO_ITQ 10

__global__ __launch_bounds__(256, 4) void topk_mono_kernel(
    const float* __restrict__ logit, const int* __restrict__ target,
    const float* __restrict__ lcn, const int* __restrict__ kpc,
    float* __restrict__ out, int B) {
    __shared__ unsigned candk[4][MONO_CAP];
    __shared__ unsigned short candi[4][MONO_CAP];
    __shared__ unsigned hist[256];
    __shared__ unsigned sh_nb[4];
    __shared__ float red_a[4], red_b[4];
    __shared__ float sh_thresh;

    const int tid = threadIdx.x;
    const int lane = tid & 63;
    const int wid = tid >> 6;
    const int row = blockIdx.x;
    const float* lrow = logit + (size_t)row * C_DIM;

    const int t = target[row];
    int k = kpc[t]; if (k > C_DIM) k = C_DIM;
    const float logit_t = lrow[t];
    const float lcn_t = lcn[t];

    unsigned* ck = candk[wid];
    unsigned short* ci = candi[wid];
    const int base4 = wid * MONO_SEGQ;

    float4 fv[MONO_ITQ], lv[MONO_ITQ];
    #pragma unroll
    for (int it = 0; it < MONO_ITQ; ++it) {
        const int j4l = it * 64 + lane;
        if (j4l < MONO_SEGQ) {
            fv[it] = ((const float4*)lrow)[base4 + j4l];
            lv[it] = ((const float4*)lcn)[base4 + j4l];
        } else {
            fv[it] = make_float4(-1e30f, -1e30f, -1e30f, -1e30f);
            lv[it] = make_float4(0.f, 0.f, 0.f, 0.f);
        }
    }

    float z0 = 0.f, z1 = 0.f, z2 = 0.f, z3 = 0.f;
    float mA = -__builtin_inff(), mB = -__builtin_inff();
    unsigned nb = 0u;
    #pragma unroll
    for (int it = 0; it < MONO_ITQ; ++it) {
        const float4 f = fv[it], l = lv[it];
        const float a0 = f.x + TAU * l.x, a1 = f.y + TAU * l.y;
        const float a2 = f.z + TAU * l.z, a3 = f.w + TAU * l.w;
        z0 += __expf(a0); z1 += __expf(a1);
        z2 += __expf(a2); z3 += __expf(a3);
        mA = fmaxf(mA, fmaxf(a0, a1));
        mB = fmaxf(mB, fmaxf(a2, a3));
        const int j = 4 * (base4 + it * 64 + lane);
        unsigned long long m;
        m = __ballot(f.x >= PIV_HI);
        if (f.x >= PIV_HI) { unsigned p = nb + (unsigned)mbcnt64(m); if (p < MONO_CAP) { ck[p] = __float_as_uint(f.x); ci[p] = (unsigned short)(j + 0); } }
        nb += (unsigned)__popcll(m);
        m = __ballot(f.y >= PIV_HI);
        if (f.y >= PIV_HI) { unsigned p = nb + (unsigned)mbcnt64(m); if (p < MONO_CAP) { ck[p] = __float_as_uint(f.y); ci[p] = (unsigned short)(j + 1); } }
        nb += (unsigned)__popcll(m);
        m = __ballot(f.z >= PIV_HI);
        if (f.z >= PIV_HI) { unsigned p = nb + (unsigned)mbcnt64(m); if (p < MONO_CAP) { ck[p] = __float_as_uint(f.z); ci[p] = (unsigned short)(j + 2); } }
        nb += (unsigned)__popcll(m);
        m = __ballot(f.w >= PIV_HI);
        if (f.w >= PIV_HI) { unsigned p = nb + (unsigned)mbcnt64(m); if (p < MONO_CAP) { ck[p] = __float_as_uint(f.w); ci[p] = (unsigned short)(j + 3); } }
        nb += (unsigned)__popcll(m);
    }
    float z = (z0 + z1) + (z2 + z3);
    float madj = fmaxf(mA, mB);
    #pragma unroll
    for (int off = 32; off; off >>= 1) madj = fmaxf(madj, __shfl_xor(madj, off));
    if (lane == 0) { red_a[wid] = madj; sh_nb[wid] = nb; }
    __syncthreads();

    const float madjB = fmaxf(fmaxf(red_a[0], red_a[1]), fmaxf(red_a[2], red_a[3]));
    unsigned nbs0 = sh_nb[0], nbs1 = sh_nb[1], nbs2 = sh_nb[2], nbs3 = sh_nb[3];
    unsigned ntot = nbs0 + nbs1 + nbs2 + nbs3;
    unsigned nmax = max(max(nbs0, nbs1), max(nbs2, nbs3));
    int path = (ntot >= (unsigned)k && nmax <= MONO_CAP) ? 0 : 2;

    if (path == 0) {
        if (wid == 0) {
            unsigned prefix = 0u, kr = (unsigned)k, cnt = ntot, kmask = 0u;
            const unsigned nbs[4] = {nbs0, nbs1, nbs2, nbs3};
            for (int q = 0; q < 4; ++q) {
                if (cnt == 1u) break;
                const int shift = 24 - 8 * q;
                *(uint4*)&hist[4 * lane] = make_uint4(0u, 0u, 0u, 0u);
                #pragma unroll
                for (int s = 0; s < 4; ++s) {
                    for (int i = lane; i < (int)nbs[s]; i += 64) {
                        unsigned kk = candk[s][i];
                        if ((kk & kmask) == prefix) atomicAdd(&hist[(kk >> shift) & 0xFFu], 1u);
                    }
                }
                uint4 hv = *(const uint4*)&hist[4 * lane];
                wave_pick(hv, lane, shift, prefix, kr, cnt);
                kmask |= (0xFFu << shift);
            }
            if (cnt == 1u && kmask != 0xFFFFFFFFu) {
                unsigned found = 0u;
                #pragma unroll
                for (int s = 0; s < 4; ++s) {
                    for (int i = lane; i < (int)nbs[s]; i += 64) {
                        unsigned kk = candk[s][i];
                        if ((kk & kmask) == prefix) found = kk;
                    }
                }
                #pragma unroll
                for (int off = 32; off; off >>= 1) found |= (unsigned)__shfl_xor((int)found, off);
                prefix = found;
            }
            if (lane == 0) sh_thresh = __uint_as_float(prefix);
        }
    } else {
        if (wid == 0) {
            unsigned prefix = 0u, kr = (unsigned)k, cnt = 0u;
            for (int p = 0; p < 4; ++p) {
                const int shift = 24 - 8 * p;
                const unsigned pmask = p ? (0xFFFFFFFFu << (shift + 8)) : 0u;
                *(uint4*)&hist[4 * lane] = make_uint4(0u, 0u, 0u, 0u);
                for (int it = 0; it < NIT4; ++it) {
                    const int j4 = it * 64 + lane;
                    if (j4 < C4) {
                        float4 f = ((const float4*)lrow)[j4];
                        unsigned kk;
                        kk = flip_key(f.x); if ((kk & pmask) == prefix) atomicAdd(&hist[(kk >> shift) & 0xFFu], 1u);
                        kk = flip_key(f.y); if ((kk & pmask) == prefix) atomicAdd(&hist[(kk >> shift) & 0xFFu], 1u);
                        kk = flip_key(f.z); if ((kk & pmask) == prefix) atomicAdd(&hist[(kk >> shift) & 0xFFu], 1u);
                        kk = flip_key(f.w); if ((kk & pmask) == prefix) atomicAdd(&hist[(kk >> shift) & 0xFFu], 1u);
                    }
                }
                uint4 hv = *(const uint4*)&hist[4 * lane];
                wave_pick(hv, lane, shift, prefix, kr, cnt);
            }
            if (lane == 0) sh_thresh = unflip_key(prefix);
        }
    }
    __syncthreads();
    const float thresh = sh_thresh;

    const bool rare = fabsf(madjB) > 80.f;
    float sm = 0.f;
    if (!rare) {
        if (path == 0) {
            const int nc = (int)sh_nb[wid];
            for (int i = lane; i < nc; i += 64) {
                const float v = __uint_as_float(ck[i]);
                if (v >= thresh) sm += __expf(v + TAU * lcn[ci[i]]);
            }
        } else {
            for (int it = 0; it < MONO_ITQ; ++it) {
                const int j4l = it * 64 + lane;
                if (j4l < MONO_SEGQ) {
                    float4 f = ((const float4*)lrow)[base4 + j4l];
                    float4 l = ((const float4*)lcn)[base4 + j4l];
                    if (f.x >= thresh) sm += __expf(f.x + TAU * l.x);
                    if (f.y >= thresh) sm += __expf(f.y + TAU * l.y);
                    if (f.z >= thresh) sm += __expf(f.z + TAU * l.z);
                    if (f.w >= thresh) sm += __expf(f.w + TAU * l.w);
                }
            }
        }
    } else {
        z = 0.f;
        for (int it = 0; it < MONO_ITQ; ++it) {
            const int j4l = it * 64 + lane;
            if (j4l < MONO_SEGQ) {
                float4 f = ((const float4*)lrow)[base4 + j4l];
                float4 l = ((const float4*)lcn)[base4 + j4l];
                float e;
                e = __expf(f.x + TAU * l.x - madjB); z += e; if (f.x >= thresh) sm += e;
                e = __expf(f.y + TAU * l.y - madjB); z += e; if (f.y >= thresh) sm += e;
                e = __expf(f.z + TAU * l.z - madjB); z += e; if (f.z >= thresh) sm += e;
                e = __expf(f.w + TAU * l.w - madjB); z += e; if (f.w >= thresh) sm += e;
            }
        }
    }

    #pragma unroll
    for (int off = 32; off; off >>= 1) {
        z  += __shfl_down(z, off);
        sm += __shfl_down(sm, off);
    }
    if (lane == 0) { red_a[wid] = z; red_b[wid] = sm; }
    __syncthreads();

    if (tid == 0) {
        const float Z = red_a[0] + red_a[1] + red_a[2] + red_a[3];
        const float S = red_b[0] + red_b[1] + red_b[2] + red_b[3];
        const float adj_t = logit_t + TAU * lcn_t;
        const float sub = rare ? madjB : 0.f;
        const float lpt = adj_t - sub - __logf(Z);
        const float p_num = ((logit_t >= thresh) ? __expf(lpt) : 0.f) + 1e-6f;
        const float Smask = S / Z + (float)C_DIM * 1e-6f;
        const float loss = 0.5f * (-lpt + __logf(Smask) - __logf(p_num));
        atomicAdd(out, loss / (float)B);
    }
}

extern "C" void kernel_launch(void* const* d_in, const int* in_sizes, int n_in,
                              void* d_out, int out_size, void* d_ws, size_t ws_size,
                              hipStream_t stream) {
    const float* logit  = (const float*)d_in[0];
    const int*   target = (const int*)d_in[1];
    const float* lcn    = (const float*)d_in[2];
    const int*   kpc    = (const int*)d_in[3];
    float* out = (float*)d_out;
    const int B = in_sizes[1];   // target is [B]

    zero_out_kernel<<<1, 64, 0, stream>>>(out, out_size);

    const size_t keys_b = (size_t)B * ROWCAP * sizeof(unsigned);
    const size_t idx_b  = (size_t)B * ROWCAP * sizeof(unsigned short);
    const size_t cnt_b  = (size_t)B * 2 * sizeof(unsigned);
    const size_t z_b    = (size_t)B * 2 * sizeof(float);
    const size_t need   = keys_b + idx_b + cnt_b + z_b + z_b;

    if (d_ws != nullptr && ws_size >= need) {
        char* wsb = (char*)d_ws;
        unsigned* g_keys       = (unsigned*)wsb;
        unsigned short* g_idx  = (unsigned short*)(wsb + keys_b);
        unsigned* g_cnt        = (unsigned*)(wsb + keys_b + idx_b);
        float* g_z             = (float*)(wsb + keys_b + idx_b + cnt_b);
        float* g_m             = (float*)(wsb + keys_b + idx_b + cnt_b + z_b);
        sweep_kernel<<<2 * B, 256, 0, stream>>>(logit, lcn, g_keys, g_idx, g_cnt, g_z, g_m);
        select_kernel<<<B, 64, 0, stream>>>(logit, target, lcn, kpc,
                                            g_keys, g_idx, g_cnt, g_z, g_m, out, B);
    } else {
        topk_mono_kernel<<<B, 256, 0, stream>>>(logit, target, lcn, kpc, out, B);
    }
}